// Round 10
// baseline (586.728 us; speedup 1.0000x reference)
//
#include <hip/hip_runtime.h>
#include <hip/hip_fp16.h>

#define N_TOK 8192
#define DDIM  1024
#define HDIM  4096
#define NEXP  8
#define NPAIR (N_TOK*2)

typedef unsigned short u16;
typedef _Float16 f16x8 __attribute__((ext_vector_type(8)));
typedef float    f32x4 __attribute__((ext_vector_type(4)));
typedef unsigned short u16x8 __attribute__((ext_vector_type(8)));

__device__ inline u16 f2h_bits(float f){
  _Float16 h = (_Float16)f;
  return __builtin_bit_cast(unsigned short, h);
}
__device__ inline float h2f(u16 b){
  _Float16 h = __builtin_bit_cast(_Float16, b);
  return (float)h;
}

typedef const __attribute__((address_space(1))) void* gas1_cvp;
typedef       __attribute__((address_space(3))) void* gas3_vp;
__device__ inline void gload_lds16(const void* g, void* l){
  __builtin_amdgcn_global_load_lds((gas1_cvp)g, (gas3_vp)l, 16, 0, 0);
}

// ---------------- gating: logits -> top2 + softmax (no atomics) ------------
__global__ __launch_bounds__(256) void gate_kernel(
    const float* __restrict__ x, const float* __restrict__ gw, const float* __restrict__ gb,
    int* __restrict__ tok_e, float* __restrict__ tok_w){
  int tok  = (int)((blockIdx.x*256u + threadIdx.x) >> 6);
  int lane = threadIdx.x & 63;
  if (tok >= N_TOK) return;
  const float* xr = x + (size_t)tok*DDIM;
  float acc[NEXP];
  #pragma unroll
  for (int e=0;e<NEXP;e++) acc[e]=0.f;
  for (int d=lane; d<DDIM; d+=64){
    float xv = xr[d];
    const float4* g4 = reinterpret_cast<const float4*>(gw + (size_t)d*NEXP);
    float4 a=g4[0], b=g4[1];
    acc[0]=fmaf(xv,a.x,acc[0]); acc[1]=fmaf(xv,a.y,acc[1]);
    acc[2]=fmaf(xv,a.z,acc[2]); acc[3]=fmaf(xv,a.w,acc[3]);
    acc[4]=fmaf(xv,b.x,acc[4]); acc[5]=fmaf(xv,b.y,acc[5]);
    acc[6]=fmaf(xv,b.z,acc[6]); acc[7]=fmaf(xv,b.w,acc[7]);
  }
  #pragma unroll
  for (int s=32;s>0;s>>=1)
    #pragma unroll
    for (int e=0;e<NEXP;e++) acc[e] += __shfl_xor(acc[e], s, 64);
  if (lane==0){
    #pragma unroll
    for (int e=0;e<NEXP;e++) acc[e]+=gb[e];
    int e0=0;
    #pragma unroll
    for (int e=1;e<NEXP;e++) if (acc[e]>acc[e0]) e0=e;   // strict >: ties -> lower idx
    int e1 = (e0==0)?1:0;
    #pragma unroll
    for (int e=0;e<NEXP;e++) if (e!=e0 && acc[e]>acc[e1]) e1=e;
    float p1 = 1.f/(1.f+__expf(acc[e0]-acc[e1]));        // softmax over top2
    float p0 = 1.f-p1;
    tok_e[tok*2]=e0; tok_e[tok*2+1]=e1;
    tok_w[tok*2]=p0; tok_w[tok*2+1]=p1;
  }
}

// ------ rank: deterministic expert-sorted positions via 1-block scan -------
__global__ __launch_bounds__(1024) void rank_kernel(
    const int* __restrict__ tok_e, const float* __restrict__ tok_w,
    int* __restrict__ offsets, int* __restrict__ perm, float* __restrict__ pairw,
    int* __restrict__ pospair){
  __shared__ u16 hist[NEXP][1024];
  __shared__ int expo[NEXP+1];
  int t = threadIdx.x;
  int c[NEXP];
  #pragma unroll
  for (int e=0;e<NEXP;e++) c[e]=0;
  int base = t*16;
  int le[16];
  #pragma unroll
  for (int i=0;i<16;i++){ le[i]=tok_e[base+i]; c[le[i]]++; }
  #pragma unroll
  for (int e=0;e<NEXP;e++) hist[e][t]=(u16)c[e];
  __syncthreads();
  for (int s=1; s<1024; s<<=1){
    u16 add[NEXP];
    #pragma unroll
    for (int e=0;e<NEXP;e++) add[e] = (t>=s)? hist[e][t-s] : (u16)0;
    __syncthreads();
    #pragma unroll
    for (int e=0;e<NEXP;e++) hist[e][t] += add[e];
    __syncthreads();
  }
  if (t==0){
    int s=0;
    #pragma unroll
    for (int e=0;e<NEXP;e++){ expo[e]=s; s+=hist[e][1023]; }
    expo[NEXP]=s;
    #pragma unroll
    for (int e=0;e<=NEXP;e++) offsets[e]=expo[e];
  }
  __syncthreads();
  int pos[NEXP];
  #pragma unroll
  for (int e=0;e<NEXP;e++) pos[e] = expo[e] + (int)hist[e][t] - c[e];
  #pragma unroll
  for (int i=0;i<16;i++){
    int e=le[i]; int p=pos[e]++;
    perm[p]=(base+i)>>1; pairw[p]=tok_w[base+i]; pospair[base+i]=p;
  }
}

// ------- gather token rows (fp32 -> fp16, expert-sorted, no atomics) -------
__global__ __launch_bounds__(256) void build_gather_kernel(
    const float* __restrict__ x, const int* __restrict__ perm, u16* __restrict__ xg){
  int pos  = (int)((blockIdx.x*256u + threadIdx.x) >> 6);
  int lane = threadIdx.x & 63;
  if (pos >= NPAIR) return;
  int tok = perm[pos];
  const float4* src = reinterpret_cast<const float4*>(x + (size_t)tok*DDIM);
  u16* dst = xg + (size_t)pos*DDIM;
  #pragma unroll
  for (int i=0;i<4;i++){
    float4 v = src[i*64+lane];
    ushort4 o;
    o.x=f2h_bits(v.x); o.y=f2h_bits(v.y); o.z=f2h_bits(v.z); o.w=f2h_bits(v.w);
    *reinterpret_cast<ushort4*>(dst + (size_t)(i*64+lane)*4) = o;
  }
}

// ------- transpose + convert: src fp32 [E][R][C] -> dst fp16 [E][C][R] -----
__global__ __launch_bounds__(256) void transpose_convert_kernel(
    const float* __restrict__ src, u16* __restrict__ dst, int R, int C){
  __shared__ float tile[64][65];
  int e = blockIdx.z;
  const float* s = src + (size_t)e*R*C;
  u16* d = dst + (size_t)e*R*C;
  int c0 = blockIdx.x*64, r0 = blockIdx.y*64;
  int t = threadIdx.x;
  int col4 = (t & 15) * 4, rrow = t >> 4;
  #pragma unroll
  for (int i=0;i<4;i++){
    int row = i*16 + rrow;
    float4 v = *reinterpret_cast<const float4*>(&s[(size_t)(r0+row)*C + c0 + col4]);
    tile[row][col4+0]=v.x; tile[row][col4+1]=v.y;
    tile[row][col4+2]=v.z; tile[row][col4+3]=v.w;
  }
  __syncthreads();
  int cIdx0 = t >> 3, r8 = (t & 7) * 8;
  #pragma unroll
  for (int j=0;j<2;j++){
    int c = j*32 + cIdx0;
    u16x8 o;
    #pragma unroll
    for (int u=0;u<8;u++) o[u] = f2h_bits(tile[r8+u][c]);
    *reinterpret_cast<u16x8*>(&d[(size_t)(c0+c)*R + r0 + r8]) = o;
  }
}

__device__ inline float gelu_tanh(float x){
  float u = 0.7978845608028654f*(x + 0.044715f*x*x*x);
  u = fminf(fmaxf(u,-9.f),9.f);
  float e2 = __expf(2.f*u);
  return 0.5f*x*(1.f + (e2-1.f)/(e2+1.f));
}

// ---------- combine: out[tok] = ybuf[pos(2tok)] + ybuf[pos(2tok+1)] --------
__global__ __launch_bounds__(256) void combine_kernel(
    const u16* __restrict__ ybuf, const int* __restrict__ pospair,
    float* __restrict__ out){
  int tok  = (int)((blockIdx.x*256u + threadIdx.x) >> 6);
  int lane = threadIdx.x & 63;
  if (tok >= N_TOK) return;
  int p0 = pospair[tok*2], p1 = pospair[tok*2+1];
  const u16x8* y0 = reinterpret_cast<const u16x8*>(ybuf + (size_t)p0*DDIM);
  const u16x8* y1 = reinterpret_cast<const u16x8*>(ybuf + (size_t)p1*DDIM);
  float4* o = reinterpret_cast<float4*>(out + (size_t)tok*DDIM);
  #pragma unroll
  for (int i=0;i<2;i++){
    u16x8 a8 = y0[i*64+lane], b8 = y1[i*64+lane];
    float4 r0, r1;
    #pragma unroll
    for (int j=0;j<4;j++){
      r0[j] = h2f(a8[j])   + h2f(b8[j]);
      r1[j] = h2f(a8[4+j]) + h2f(b8[4+j]);
    }
    o[(i*64+lane)*2]   = r0;
    o[(i*64+lane)*2+1] = r1;
  }
}

// ============ 256x128 segment GEMM (intensity-raised m97 family) ===========
// BK=32, 4 waves (2Mx2N, per-wave 128x64, acc[8][4]), 48KB double-buffered
// LDS (A 16KB + B 8KB per step), 2 blocks/CU. Staged bytes per FLOP is 2/3 of
// the 128x128 tile -> L2-BW per CU stops binding before the MFMA pipe.
// One __syncthreads per K-step (its vmcnt0 drain publishes staging;
// correctness held R7-R9). Same conflict-free subtile swizzle (R4-verified),
// swapped MFMA operands (per-thread reg j = 4 consecutive N-cols).
template<int EPI>
__global__ __launch_bounds__(256,2) void moe_gemm97(
    const u16* __restrict__ Abase, const u16* __restrict__ Btbase,
    const float* __restrict__ bias,
    u16* __restrict__ Hout, u16* __restrict__ Ybuf,
    const int* __restrict__ offsets, const float* __restrict__ pairw){
  constexpr int Kd = (EPI==0)?DDIM:HDIM;
  constexpr int Nn = (EPI==0)?HDIM:DDIM;
  constexpr int NT = Kd/32;          // K-steps (32 or 128, even, >=4)
  constexpr int BR = 16, BC = Nn/128, PER_E = BR*BC, G = NEXP*PER_E;
  __shared__ __align__(16) char lds[49152];   // [buf][A 16KB | B 8KB]

  int bid = blockIdx.x;
  int lg = (bid&7)*(G/8) + (bid>>3);          // XCD-bijective (G%8==0)
  int e = lg/PER_E, r = lg%PER_E;
  int bcol = r/BR, brow = r%BR;               // brow inner: B-tile L2 reuse
  int off = offsets[e], cnt = offsets[e+1]-off;
  if (brow*256 >= cnt) return;
  int lane = threadIdx.x&63, wid = (int)threadIdx.x>>6;
  int wr = wid>>1, wc = wid&1;                // 2x2 wave grid (M x N)

  // staging: A chunks c = wid+4j (j=0..3), B chunks c = wid+4j (j=0..1);
  // row(col) = c*16 + lane>>2, kelem = (lane&3)*8 ^ ((lane>>5)&1)*16
  // (inverse of the LDS swizzle; linear gload_lds dest = chunk-major).
  int l4 = lane>>2;
  int kof = ((lane&3)*8) ^ (((lane>>5)&1)*16);
  const u16* BtE = Btbase + (size_t)e*Nn*Kd;
  const u16* aP[4]; const u16* bP[2];
  int aDst[4], bDst[2];
  #pragma unroll
  for (int j=0;j<4;j++){
    int row = (wid+4*j)*16 + l4;
    aP[j] = Abase + (size_t)(off + min(brow*256+row, cnt-1))*Kd + kof;
    aDst[j] = (wid+4*j)*1024 + lane*16;
  }
  #pragma unroll
  for (int j=0;j<2;j++){
    int col = (wid+4*j)*16 + l4;
    bP[j] = BtE + (size_t)(bcol*128+col)*Kd + kof;
    bDst[j] = 16384 + (wid+4*j)*1024 + lane*16;
  }

#define STG(buf, t) { \
    _Pragma("unroll") \
    for (int j=0;j<4;j++) \
      gload_lds16(aP[j] + (size_t)(t)*32, lds + (buf)*24576 + aDst[j]); \
    _Pragma("unroll") \
    for (int j=0;j<2;j++) \
      gload_lds16(bP[j] + (size_t)(t)*32, lds + (buf)*24576 + bDst[j]); }

  // fragment reads (conflict-free subtile swizzle, R4-verified)
  int lr = lane&15;
  int rdq = lr*64 + (((lane>>4)*16) ^ (((lane>>3)&1)<<5));
  f32x4 acc[8][4] = {};

  // STEP: compute tile in `buf`; optionally stage tile `st` into buf^1.
#define STEP(buf, st, DOSTG) { \
    if (DOSTG) STG((buf)^1, st); \
    const char* base_ = lds + (buf)*24576; \
    f16x8 a_[8], b_[4]; \
    _Pragma("unroll") \
    for (int mf=0;mf<8;mf++) \
      a_[mf] = *reinterpret_cast<const f16x8*>(base_ + (wr*8+mf)*1024 + rdq); \
    _Pragma("unroll") \
    for (int nf=0;nf<4;nf++) \
      b_[nf] = *reinterpret_cast<const f16x8*>(base_ + 16384 + (wc*4+nf)*1024 + rdq); \
    _Pragma("unroll") \
    for (int mf=0;mf<8;mf++) \
      _Pragma("unroll") \
      for (int nf=0;nf<4;nf++) \
        acc[mf][nf] = __builtin_amdgcn_mfma_f32_16x16x32_f16(b_[nf], a_[mf], acc[mf][nf], 0,0,0); \
    __syncthreads(); }

  STG(0, 0);
  __syncthreads();
  for (int t=0; t<NT-2; t+=2){
    STEP(0, t+1, 1);
    STEP(1, t+2, 1);
  }
  STEP(0, NT-1, 1);
  STEP(1, 0, 0);
#undef STEP
#undef STG

  // epilogue (swapped layout): row = brow*256+wr*128+mf*16+(lane&15)
  //   col quad = bcol*128+wc*64+nf*16+(lane>>4)*4 + j (j=0..3 contiguous)
  int lcq = (lane>>4)*4;
  #pragma unroll
  for (int mf=0;mf<8;mf++){
    int grow = brow*256 + wr*128 + mf*16 + lr;
    if (grow < cnt){
      int p = off + grow;
      size_t rbase = (size_t)p*Nn;
      float wv = (EPI==0) ? 0.f : pairw[p];
      #pragma unroll
      for (int nf=0;nf<4;nf++){
        int colg = bcol*128 + wc*64 + nf*16 + lcq;
        float4 bv = *reinterpret_cast<const float4*>(&bias[e*Nn + colg]);
        ushort4 o;
        if (EPI==0){
          o.x = f2h_bits(gelu_tanh(acc[mf][nf][0] + bv.x));
          o.y = f2h_bits(gelu_tanh(acc[mf][nf][1] + bv.y));
          o.z = f2h_bits(gelu_tanh(acc[mf][nf][2] + bv.z));
          o.w = f2h_bits(gelu_tanh(acc[mf][nf][3] + bv.w));
          *reinterpret_cast<ushort4*>(&Hout[rbase + colg]) = o;
        } else {
          o.x = f2h_bits(wv*(acc[mf][nf][0] + bv.x));
          o.y = f2h_bits(wv*(acc[mf][nf][1] + bv.y));
          o.z = f2h_bits(wv*(acc[mf][nf][2] + bv.z));
          o.w = f2h_bits(wv*(acc[mf][nf][3] + bv.w));
          *reinterpret_cast<ushort4*>(&Ybuf[rbase + colg]) = o;
        }
      }
    }
  }
}

extern "C" void kernel_launch(void* const* d_in, const int* in_sizes, int n_in,
                              void* d_out, int out_size, void* d_ws, size_t ws_size,
                              hipStream_t stream){
  const float* x  = (const float*)d_in[0];
  const float* gw = (const float*)d_in[1];
  const float* gb = (const float*)d_in[2];
  const float* w1 = (const float*)d_in[3];
  const float* b1 = (const float*)d_in[4];
  const float* w2 = (const float*)d_in[5];
  const float* b2 = (const float*)d_in[6];
  float* out = (float*)d_out;
  char* ws = (char*)d_ws;

  // workspace layout
  int*   offsets = (int*)(ws + 64);
  int*   tok_e   = (int*)(ws + 256);
  float* tok_w   = (float*)(ws + 256 + 1*65536);
  int*   perm    = (int*)(ws + 256 + 2*65536);
  float* pairw   = (float*)(ws + 256 + 3*65536);
  int*   pospair = (int*)(ws + 256 + 4*65536);
  size_t base = 256 + 5*65536;
  u16* xg   = (u16*)(ws + base);                                     // 32 MiB
  u16* w1t  = (u16*)(ws + base + 33554432ull);                       // 64 MiB
  u16* w2t  = (u16*)(ws + base + 33554432ull + 67108864ull);         // 64 MiB
  u16* hbuf = (u16*)(ws + base + 33554432ull + 2*67108864ull);       // 128 MiB
  u16* ybuf = xg;   // xg dead after GEMM1; reuse as per-pair output (32 MiB)
  size_t need = base + 33554432ull + 2*67108864ull + 134217728ull;

  if (ws_size < need){   // graceful fail: zeros out
    hipMemsetAsync(d_out, 0, (size_t)out_size*sizeof(float), stream);
    return;
  }

  gate_kernel<<<N_TOK/4, 256, 0, stream>>>(x, gw, gb, tok_e, tok_w);
  rank_kernel<<<1, 1024, 0, stream>>>(tok_e, tok_w, offsets, perm, pairw, pospair);
  build_gather_kernel<<<NPAIR/4, 256, 0, stream>>>(x, perm, xg);
  transpose_convert_kernel<<<dim3(HDIM/64, DDIM/64, NEXP), 256, 0, stream>>>(w1, w1t, DDIM, HDIM);
  transpose_convert_kernel<<<dim3(DDIM/64, HDIM/64, NEXP), 256, 0, stream>>>(w2, w2t, HDIM, DDIM);
  moe_gemm97<0><<<NEXP*16*(HDIM/128), 256, 0, stream>>>(
      xg, w1t, b1, hbuf, nullptr, offsets, pairw);
  moe_gemm97<1><<<NEXP*16*(DDIM/128), 256, 0, stream>>>(
      hbuf, w2t, b2, nullptr, ybuf, offsets, pairw);
  combine_kernel<<<N_TOK/4, 256, 0, stream>>>(ybuf, pospair, out);
}

// Round 11
// 581.291 us; speedup vs baseline: 1.0094x; 1.0094x over previous
//
#include <hip/hip_runtime.h>
#include <hip/hip_fp16.h>

#define N_TOK 8192
#define DDIM  1024
#define HDIM  4096
#define NEXP  8
#define NPAIR (N_TOK*2)

typedef unsigned short u16;
typedef _Float16 f16x8 __attribute__((ext_vector_type(8)));
typedef float    f32x4 __attribute__((ext_vector_type(4)));
typedef unsigned short u16x8 __attribute__((ext_vector_type(8)));

__device__ inline u16 f2h_bits(float f){
  _Float16 h = (_Float16)f;
  return __builtin_bit_cast(unsigned short, h);
}
__device__ inline float h2f(u16 b){
  _Float16 h = __builtin_bit_cast(_Float16, b);
  return (float)h;
}

typedef const __attribute__((address_space(1))) void* gas1_cvp;
typedef       __attribute__((address_space(3))) void* gas3_vp;
__device__ inline void gload_lds16(const void* g, void* l){
  __builtin_amdgcn_global_load_lds((gas1_cvp)g, (gas3_vp)l, 16, 0, 0);
}

// ---------------- gating: logits -> top2 + softmax (no atomics) ------------
__global__ __launch_bounds__(256) void gate_kernel(
    const float* __restrict__ x, const float* __restrict__ gw, const float* __restrict__ gb,
    int* __restrict__ tok_e, float* __restrict__ tok_w){
  int tok  = (int)((blockIdx.x*256u + threadIdx.x) >> 6);
  int lane = threadIdx.x & 63;
  if (tok >= N_TOK) return;
  const float* xr = x + (size_t)tok*DDIM;
  float acc[NEXP];
  #pragma unroll
  for (int e=0;e<NEXP;e++) acc[e]=0.f;
  for (int d=lane; d<DDIM; d+=64){
    float xv = xr[d];
    const float4* g4 = reinterpret_cast<const float4*>(gw + (size_t)d*NEXP);
    float4 a=g4[0], b=g4[1];
    acc[0]=fmaf(xv,a.x,acc[0]); acc[1]=fmaf(xv,a.y,acc[1]);
    acc[2]=fmaf(xv,a.z,acc[2]); acc[3]=fmaf(xv,a.w,acc[3]);
    acc[4]=fmaf(xv,b.x,acc[4]); acc[5]=fmaf(xv,b.y,acc[5]);
    acc[6]=fmaf(xv,b.z,acc[6]); acc[7]=fmaf(xv,b.w,acc[7]);
  }
  #pragma unroll
  for (int s=32;s>0;s>>=1)
    #pragma unroll
    for (int e=0;e<NEXP;e++) acc[e] += __shfl_xor(acc[e], s, 64);
  if (lane==0){
    #pragma unroll
    for (int e=0;e<NEXP;e++) acc[e]+=gb[e];
    int e0=0;
    #pragma unroll
    for (int e=1;e<NEXP;e++) if (acc[e]>acc[e0]) e0=e;   // strict >: ties -> lower idx
    int e1 = (e0==0)?1:0;
    #pragma unroll
    for (int e=0;e<NEXP;e++) if (e!=e0 && acc[e]>acc[e1]) e1=e;
    float p1 = 1.f/(1.f+__expf(acc[e0]-acc[e1]));        // softmax over top2
    float p0 = 1.f-p1;
    tok_e[tok*2]=e0; tok_e[tok*2+1]=e1;
    tok_w[tok*2]=p0; tok_w[tok*2+1]=p1;
  }
}

// ------ rank: deterministic expert-sorted positions via 1-block scan -------
__global__ __launch_bounds__(1024) void rank_kernel(
    const int* __restrict__ tok_e, const float* __restrict__ tok_w,
    int* __restrict__ offsets, int* __restrict__ perm, float* __restrict__ pairw,
    int* __restrict__ pospair){
  __shared__ u16 hist[NEXP][1024];
  __shared__ int expo[NEXP+1];
  int t = threadIdx.x;
  int c[NEXP];
  #pragma unroll
  for (int e=0;e<NEXP;e++) c[e]=0;
  int base = t*16;
  int le[16];
  #pragma unroll
  for (int i=0;i<16;i++){ le[i]=tok_e[base+i]; c[le[i]]++; }
  #pragma unroll
  for (int e=0;e<NEXP;e++) hist[e][t]=(u16)c[e];
  __syncthreads();
  for (int s=1; s<1024; s<<=1){
    u16 add[NEXP];
    #pragma unroll
    for (int e=0;e<NEXP;e++) add[e] = (t>=s)? hist[e][t-s] : (u16)0;
    __syncthreads();
    #pragma unroll
    for (int e=0;e<NEXP;e++) hist[e][t] += add[e];
    __syncthreads();
  }
  if (t==0){
    int s=0;
    #pragma unroll
    for (int e=0;e<NEXP;e++){ expo[e]=s; s+=hist[e][1023]; }
    expo[NEXP]=s;
    #pragma unroll
    for (int e=0;e<=NEXP;e++) offsets[e]=expo[e];
  }
  __syncthreads();
  int pos[NEXP];
  #pragma unroll
  for (int e=0;e<NEXP;e++) pos[e] = expo[e] + (int)hist[e][t] - c[e];
  #pragma unroll
  for (int i=0;i<16;i++){
    int e=le[i]; int p=pos[e]++;
    perm[p]=(base+i)>>1; pairw[p]=tok_w[base+i]; pospair[base+i]=p;
  }
}

// ------- gather token rows (fp32 -> fp16, expert-sorted, no atomics) -------
__global__ __launch_bounds__(256) void build_gather_kernel(
    const float* __restrict__ x, const int* __restrict__ perm, u16* __restrict__ xg){
  int pos  = (int)((blockIdx.x*256u + threadIdx.x) >> 6);
  int lane = threadIdx.x & 63;
  if (pos >= NPAIR) return;
  int tok = perm[pos];
  const float4* src = reinterpret_cast<const float4*>(x + (size_t)tok*DDIM);
  u16* dst = xg + (size_t)pos*DDIM;
  #pragma unroll
  for (int i=0;i<4;i++){
    float4 v = src[i*64+lane];
    ushort4 o;
    o.x=f2h_bits(v.x); o.y=f2h_bits(v.y); o.z=f2h_bits(v.z); o.w=f2h_bits(v.w);
    *reinterpret_cast<ushort4*>(dst + (size_t)(i*64+lane)*4) = o;
  }
}

// ------- transpose + convert: src fp32 [E][R][C] -> dst fp16 [E][C][R] -----
__global__ __launch_bounds__(256) void transpose_convert_kernel(
    const float* __restrict__ src, u16* __restrict__ dst, int R, int C){
  __shared__ float tile[64][65];
  int e = blockIdx.z;
  const float* s = src + (size_t)e*R*C;
  u16* d = dst + (size_t)e*R*C;
  int c0 = blockIdx.x*64, r0 = blockIdx.y*64;
  int t = threadIdx.x;
  int col4 = (t & 15) * 4, rrow = t >> 4;
  #pragma unroll
  for (int i=0;i<4;i++){
    int row = i*16 + rrow;
    float4 v = *reinterpret_cast<const float4*>(&s[(size_t)(r0+row)*C + c0 + col4]);
    tile[row][col4+0]=v.x; tile[row][col4+1]=v.y;
    tile[row][col4+2]=v.z; tile[row][col4+3]=v.w;
  }
  __syncthreads();
  int cIdx0 = t >> 3, r8 = (t & 7) * 8;
  #pragma unroll
  for (int j=0;j<2;j++){
    int c = j*32 + cIdx0;
    u16x8 o;
    #pragma unroll
    for (int u=0;u<8;u++) o[u] = f2h_bits(tile[r8+u][c]);
    *reinterpret_cast<u16x8*>(&d[(size_t)(c0+c)*R + r0 + r8]) = o;
  }
}

__device__ inline float gelu_tanh(float x){
  float u = 0.7978845608028654f*(x + 0.044715f*x*x*x);
  u = fminf(fmaxf(u,-9.f),9.f);
  float e2 = __expf(2.f*u);
  return 0.5f*x*(1.f + (e2-1.f)/(e2+1.f));
}

// ---------- combine: out[tok] = ybuf[pos(2tok)] + ybuf[pos(2tok+1)] --------
__global__ __launch_bounds__(256) void combine_kernel(
    const u16* __restrict__ ybuf, const int* __restrict__ pospair,
    float* __restrict__ out){
  int tok  = (int)((blockIdx.x*256u + threadIdx.x) >> 6);
  int lane = threadIdx.x & 63;
  if (tok >= N_TOK) return;
  int p0 = pospair[tok*2], p1 = pospair[tok*2+1];
  const u16x8* y0 = reinterpret_cast<const u16x8*>(ybuf + (size_t)p0*DDIM);
  const u16x8* y1 = reinterpret_cast<const u16x8*>(ybuf + (size_t)p1*DDIM);
  float4* o = reinterpret_cast<float4*>(out + (size_t)tok*DDIM);
  #pragma unroll
  for (int i=0;i<2;i++){
    u16x8 a8 = y0[i*64+lane], b8 = y1[i*64+lane];
    float4 r0, r1;
    #pragma unroll
    for (int j=0;j<4;j++){
      r0[j] = h2f(a8[j])   + h2f(b8[j]);
      r1[j] = h2f(a8[4+j]) + h2f(b8[4+j]);
    }
    o[(i*64+lane)*2]   = r0;
    o[(i*64+lane)*2+1] = r1;
  }
}

// ====== 128x128 segment GEMM: m97 body + counted-vmcnt barrier (T4) ========
// BK=32, 4 waves (2x2, per-wave 64x64), TRIPLE-buffered 48KB LDS, 3 blk/CU.
// Per step: stage tile t+2 into ps (4 gload_lds/thread), ds_read+16 MFMA from
// pc (compiler's fine-grained lgkmcnt — no barrier between read and MFMA),
// then vmcnt(4)+s_barrier: retires ONLY tile t+1's loads (issued a full step
// ago, ~400+cyc slack) and leaves tile t+2's 4 loads in flight across the
// barrier. This removes R7-R10's per-step vmcnt(0) drain (__syncthreads),
// the stall that pinned MfmaUtil at ~26%. Cross-wave safety: every wave
// passes its own vmcnt(4) before the barrier => at barrier-exit the next
// buffer is fully written (R6-verified ledger discipline); the staging target
// ps is not read until two barriers later. Tail stages wrapped tiles
// (redundant, L2-hot) to keep the ledger uniform; vmcnt(0) before epilogue.
template<int EPI>
__global__ __launch_bounds__(256,3) void moe_gemm97(
    const u16* __restrict__ Abase, const u16* __restrict__ Btbase,
    const float* __restrict__ bias,
    u16* __restrict__ Hout, u16* __restrict__ Ybuf,
    const int* __restrict__ offsets, const float* __restrict__ pairw){
  constexpr int Kd = (EPI==0)?DDIM:HDIM;
  constexpr int Nn = (EPI==0)?HDIM:DDIM;
  constexpr int NT = Kd/32;          // K-steps (32 or 128, pow2)
  constexpr int BR = 32, BC = Nn/128, PER_E = BR*BC, G = NEXP*PER_E;
  __shared__ __align__(16) char lds[49152];   // 3 x [A 8KB | B 8KB]

  int bid = blockIdx.x;
  int lg = (bid&7)*(G/8) + (bid>>3);          // XCD-bijective (G%8==0)
  int e = lg/PER_E, r = lg%PER_E;
  int bcol = r/BR, brow = r%BR;               // brow inner: B-tile L2 reuse
  int off = offsets[e], cnt = offsets[e+1]-off;
  if (brow*128 >= cnt) return;
  int lane = threadIdx.x&63, wid = (int)threadIdx.x>>6;
  int wr = wid>>1, wc = wid&1;                // 2x2 wave grid

  // staging: chunks c = wid, wid+4; row = c*16 + lane>>2,
  // kelem = (lane&3)*8 ^ ((lane>>5)&1)*16  (inverse of the LDS swizzle)
  int l4 = lane>>2;
  int kof = ((lane&3)*8) ^ (((lane>>5)&1)*16);
  int row0 = wid*16 + l4, row1 = (wid+4)*16 + l4;
  const u16* BtE = Btbase + (size_t)e*Nn*Kd;
  const u16* aP0 = Abase + (size_t)(off + min(brow*128+row0, cnt-1))*Kd + kof;
  const u16* aP1 = Abase + (size_t)(off + min(brow*128+row1, cnt-1))*Kd + kof;
  const u16* bP0 = BtE + (size_t)(bcol*128+row0)*Kd + kof;
  const u16* bP1 = BtE + (size_t)(bcol*128+row1)*Kd + kof;
  int dst0 = wid*1024 + lane*16, dst1 = (wid+4)*1024 + lane*16;

#define STG(P, t) { \
    gload_lds16(aP0 + (size_t)(t)*32, (P) + dst0); \
    gload_lds16(aP1 + (size_t)(t)*32, (P) + dst1); \
    gload_lds16(bP0 + (size_t)(t)*32, (P) + 8192 + dst0); \
    gload_lds16(bP1 + (size_t)(t)*32, (P) + 8192 + dst1); }

#define VM4 { asm volatile("s_waitcnt vmcnt(4)" ::: "memory"); \
              __builtin_amdgcn_sched_barrier(0); }
#define VM0 { asm volatile("s_waitcnt vmcnt(0)" ::: "memory"); \
              __builtin_amdgcn_sched_barrier(0); }
#define BARR { __builtin_amdgcn_s_barrier(); \
               __builtin_amdgcn_sched_barrier(0); }

  // fragment reads (conflict-free subtile swizzle, R4-verified)
  int lr = lane&15;
  int rdq = lr*64 + (((lane>>4)*16) ^ (((lane>>3)&1)<<5));
  f32x4 acc[4][4] = {};

  char* pc = lds;            // compute buffer (tile t)
  char* pn = lds + 16384;    // next (tile t+1, in flight or landed)
  char* ps = lds + 32768;    // stage target (tile t+2)

  STG(pc, 0); STG(pn, 1);
  VM4; BARR;                 // tile0 landed; tile1's 4 loads stay in flight

  for (int t=0; t<NT; ++t){
    STG(ps, (t+2)&(NT-1));   // wrapped past NT-1: redundant, never read
    f16x8 a_[4], b_[4];
    #pragma unroll
    for (int mf=0;mf<4;mf++)
      a_[mf] = *reinterpret_cast<const f16x8*>(pc + (wr*4+mf)*1024 + rdq);
    #pragma unroll
    for (int nf=0;nf<4;nf++)
      b_[nf] = *reinterpret_cast<const f16x8*>(pc + 8192 + (wc*4+nf)*1024 + rdq);
    #pragma unroll
    for (int mf=0;mf<4;mf++)
      #pragma unroll
      for (int nf=0;nf<4;nf++)
        acc[mf][nf] = __builtin_amdgcn_mfma_f32_16x16x32_f16(b_[nf], a_[mf], acc[mf][nf], 0,0,0);
    VM4;                     // retire tile t+1's loads (issued last step)
    BARR;                    // next buffer now valid for every wave
    char* tmp = pc; pc = pn; pn = ps; ps = tmp;
  }
  VM0;   // drain wrapped tail stages before LDS goes out of scope
#undef STG
#undef VM4
#undef VM0
#undef BARR

  // epilogue (swapped layout): row = brow*128+wr*64+mf*16+(lane&15)
  //   col quad = bcol*128+wc*64+nf*16+(lane>>4)*4 + j (j=0..3 contiguous)
  int lcq = (lane>>4)*4;
  #pragma unroll
  for (int mf=0;mf<4;mf++){
    int grow = brow*128 + wr*64 + mf*16 + lr;
    if (grow < cnt){
      int p = off + grow;
      size_t rbase = (size_t)p*Nn;
      float wv = (EPI==0) ? 0.f : pairw[p];
      #pragma unroll
      for (int nf=0;nf<4;nf++){
        int colg = bcol*128 + wc*64 + nf*16 + lcq;
        float4 bv = *reinterpret_cast<const float4*>(&bias[e*Nn + colg]);
        ushort4 o;
        if (EPI==0){
          o.x = f2h_bits(gelu_tanh(acc[mf][nf][0] + bv.x));
          o.y = f2h_bits(gelu_tanh(acc[mf][nf][1] + bv.y));
          o.z = f2h_bits(gelu_tanh(acc[mf][nf][2] + bv.z));
          o.w = f2h_bits(gelu_tanh(acc[mf][nf][3] + bv.w));
          *reinterpret_cast<ushort4*>(&Hout[rbase + colg]) = o;
        } else {
          o.x = f2h_bits(wv*(acc[mf][nf][0] + bv.x));
          o.y = f2h_bits(wv*(acc[mf][nf][1] + bv.y));
          o.z = f2h_bits(wv*(acc[mf][nf][2] + bv.z));
          o.w = f2h_bits(wv*(acc[mf][nf][3] + bv.w));
          *reinterpret_cast<ushort4*>(&Ybuf[rbase + colg]) = o;
        }
      }
    }
  }
}

extern "C" void kernel_launch(void* const* d_in, const int* in_sizes, int n_in,
                              void* d_out, int out_size, void* d_ws, size_t ws_size,
                              hipStream_t stream){
  const float* x  = (const float*)d_in[0];
  const float* gw = (const float*)d_in[1];
  const float* gb = (const float*)d_in[2];
  const float* w1 = (const float*)d_in[3];
  const float* b1 = (const float*)d_in[4];
  const float* w2 = (const float*)d_in[5];
  const float* b2 = (const float*)d_in[6];
  float* out = (float*)d_out;
  char* ws = (char*)d_ws;

  // workspace layout
  int*   offsets = (int*)(ws + 64);
  int*   tok_e   = (int*)(ws + 256);
  float* tok_w   = (float*)(ws + 256 + 1*65536);
  int*   perm    = (int*)(ws + 256 + 2*65536);
  float* pairw   = (float*)(ws + 256 + 3*65536);
  int*   pospair = (int*)(ws + 256 + 4*65536);
  size_t base = 256 + 5*65536;
  u16* xg   = (u16*)(ws + base);                                     // 32 MiB
  u16* w1t  = (u16*)(ws + base + 33554432ull);                       // 64 MiB
  u16* w2t  = (u16*)(ws + base + 33554432ull + 67108864ull);         // 64 MiB
  u16* hbuf = (u16*)(ws + base + 33554432ull + 2*67108864ull);       // 128 MiB
  u16* ybuf = xg;   // xg dead after GEMM1; reuse as per-pair output (32 MiB)
  size_t need = base + 33554432ull + 2*67108864ull + 134217728ull;

  if (ws_size < need){   // graceful fail: zeros out
    hipMemsetAsync(d_out, 0, (size_t)out_size*sizeof(float), stream);
    return;
  }

  gate_kernel<<<N_TOK/4, 256, 0, stream>>>(x, gw, gb, tok_e, tok_w);
  rank_kernel<<<1, 1024, 0, stream>>>(tok_e, tok_w, offsets, perm, pairw, pospair);
  build_gather_kernel<<<NPAIR/4, 256, 0, stream>>>(x, perm, xg);
  transpose_convert_kernel<<<dim3(HDIM/64, DDIM/64, NEXP), 256, 0, stream>>>(w1, w1t, DDIM, HDIM);
  transpose_convert_kernel<<<dim3(DDIM/64, HDIM/64, NEXP), 256, 0, stream>>>(w2, w2t, HDIM, DDIM);
  moe_gemm97<0><<<NEXP*32*(HDIM/128), 256, 0, stream>>>(
      xg, w1t, b1, hbuf, nullptr, offsets, pairw);
  moe_gemm97<1><<<NEXP*32*(DDIM/128), 256, 0, stream>>>(
      hbuf, w2t, b2, nullptr, ybuf, offsets, pairw);
  combine_kernel<<<N_TOK/4, 256, 0, stream>>>(ybuf, pospair, out);
}